// Round 14
// baseline (1360.342 us; speedup 1.0000x reference)
//
#include <hip/hip_runtime.h>
#include <math.h>

#define WH 7
#define WW 7
#define NN 49
#define HEADS 12
#define HD 32
#define CC 384
#define NW 256

typedef short s16x8 __attribute__((ext_vector_type(8)));
typedef unsigned short u16x8 __attribute__((ext_vector_type(8)));
typedef float f32x4 __attribute__((ext_vector_type(4)));

// fp32 -> bf16 (round-to-nearest-even), bit-level
__device__ __forceinline__ unsigned short f2bf(float x) {
  unsigned u = __builtin_bit_cast(unsigned, x);
  u += 0x7fffu + ((u >> 16) & 1u);
  return (unsigned short)(u >> 16);
}
__device__ __forceinline__ float bf2f(unsigned short b) {
  unsigned u = ((unsigned)b) << 16;
  return __builtin_bit_cast(float, u);
}

// ---------- transpose + hi/lo split of a weight matrix ----------
// W[K][N] fp32 -> Th[N][K], Tl[N][K] bf16 bits.
// Adjacent threads read adjacent n (coalesced on W); strided writes are
// absorbed by L2 (tiny matrix, runs once per launch).
__global__ void split_wt_kernel(const float* __restrict__ W,
                                unsigned short* __restrict__ Th,
                                unsigned short* __restrict__ Tl,
                                int K, int N) {
  const int idx = blockIdx.x * 256 + threadIdx.x;
  if (idx >= K * N) return;
  const int k = idx / N, n = idx % N;
  const float v = W[idx];  // == W[k*N + n]
  const unsigned short h = f2bf(v);
  const size_t t = (size_t)n * K + k;
  Th[t] = h;
  Tl[t] = f2bf(v - bf2f(h));
}

// ---------- GEMM via bf16x3 MFMA ----------
// C[M][N] = A[M][K](fp32, split in-kernel) @ Bt[N][K](pre-split bf16) + bias
// 128x128 tile, 256 thr (4 waves as 2x2 of 64x64), K-step 32.
// 1D grid with XCD-chunked swizzle; logical = bmTile*tilesN + bnTile.
// Requires M%128==0, N%128==0, K%32==0, grid%8==0.
// NT: nontemporal C stores (use when C is never re-read device-side).
template <bool NT>
__global__ __launch_bounds__(256) void gemm_bf16x3_kernel(
    const float* __restrict__ A, const unsigned short* __restrict__ Bth,
    const unsigned short* __restrict__ Btl, const float* __restrict__ bias,
    float* __restrict__ C, int M, int N, int K, int tilesN, int chunk) {
  __shared__ unsigned short Ash[128][40];  // pad to 40 (80B rows): <=2-way
  __shared__ unsigned short Asl[128][40];
  __shared__ unsigned short Bsh[128][40];
  __shared__ unsigned short Bsl[128][40];

  // XCD-aware swizzle: hw round-robins blockIdx.x across the 8 XCDs;
  // give each XCD a contiguous chunk of logical tiles (A-panel L2 locality).
  const int lin = blockIdx.x;
  const int logical = (lin & 7) * chunk + (lin >> 3);
  const int bm = (logical / tilesN) * 128;
  const int bn = (logical % tilesN) * 128;

  const int tid = threadIdx.x;
  const int lane = tid & 63;
  const int wv = tid >> 6;
  const int wm = (wv >> 1) * 64;   // wave row base within tile
  const int wn = (wv & 1) * 64;    // wave col base
  const int fr = lane & 15;        // fragment row/col
  const int g8 = (lane >> 4) * 8;  // k-group offset (elements)

  const int srow = tid >> 1;        // staging row 0..127
  const int sc16 = (tid & 1) * 16;  // staging col offset (elements)

  f32x4 acc[4][4] = {};

  for (int k0 = 0; k0 < K; k0 += 32) {
    // --- stage A: fp32 -> hi/lo bf16 in LDS ---
    {
      const float* src = &A[(size_t)(bm + srow) * K + k0 + sc16];
      float v[16];
      *(f32x4*)&v[0] = *(const f32x4*)&src[0];
      *(f32x4*)&v[4] = *(const f32x4*)&src[4];
      *(f32x4*)&v[8] = *(const f32x4*)&src[8];
      *(f32x4*)&v[12] = *(const f32x4*)&src[12];
      unsigned short h[16], l[16];
#pragma unroll
      for (int i = 0; i < 16; ++i) {
        h[i] = f2bf(v[i]);
        l[i] = f2bf(v[i] - bf2f(h[i]));
      }
      *(u16x8*)&Ash[srow][sc16] = *(u16x8*)&h[0];
      *(u16x8*)&Ash[srow][sc16 + 8] = *(u16x8*)&h[8];
      *(u16x8*)&Asl[srow][sc16] = *(u16x8*)&l[0];
      *(u16x8*)&Asl[srow][sc16 + 8] = *(u16x8*)&l[8];
    }
    // --- stage B: pre-split bf16 hi/lo (Bt is [N][K] row-major) ---
    {
      const size_t off = (size_t)(bn + srow) * K + k0 + sc16;
      const unsigned short* sh = &Bth[off];
      const unsigned short* sl = &Btl[off];
      *(u16x8*)&Bsh[srow][sc16] = *(const u16x8*)&sh[0];
      *(u16x8*)&Bsh[srow][sc16 + 8] = *(const u16x8*)&sh[8];
      *(u16x8*)&Bsl[srow][sc16] = *(const u16x8*)&sl[0];
      *(u16x8*)&Bsl[srow][sc16 + 8] = *(const u16x8*)&sl[8];
    }
    __syncthreads();

    s16x8 ah[4], al[4];
#pragma unroll
    for (int m = 0; m < 4; ++m) {
      ah[m] = *(const s16x8*)&Ash[wm + m * 16 + fr][g8];
      al[m] = *(const s16x8*)&Asl[wm + m * 16 + fr][g8];
    }
#pragma unroll
    for (int n = 0; n < 4; ++n) {
      const s16x8 bh = *(const s16x8*)&Bsh[wn + n * 16 + fr][g8];
      const s16x8 bl = *(const s16x8*)&Bsl[wn + n * 16 + fr][g8];
#pragma unroll
      for (int m = 0; m < 4; ++m) {
        acc[m][n] = __builtin_amdgcn_mfma_f32_16x16x32_bf16(ah[m], bh,
                                                            acc[m][n], 0, 0, 0);
        acc[m][n] = __builtin_amdgcn_mfma_f32_16x16x32_bf16(ah[m], bl,
                                                            acc[m][n], 0, 0, 0);
        acc[m][n] = __builtin_amdgcn_mfma_f32_16x16x32_bf16(al[m], bh,
                                                            acc[m][n], 0, 0, 0);
      }
    }
    __syncthreads();
  }

  // epilogue: D row = (lane>>4)*4 + reg, col = lane&15  [HW-verified mapping]
  const int r0 = (lane >> 4) * 4;
#pragma unroll
  for (int m = 0; m < 4; ++m) {
#pragma unroll
    for (int r = 0; r < 4; ++r) {
      const int row = bm + wm + m * 16 + r0 + r;
      float* dst = &C[(size_t)row * N + bn + wn];
#pragma unroll
      for (int n = 0; n < 4; ++n) {
        const float val = acc[m][n][r] + bias[bn + wn + n * 16 + fr];
        if (NT)
          __builtin_nontemporal_store(val, &dst[n * 16 + fr]);
        else
          dst[n * 16 + fr] = val;
      }
    }
  }
}

// ---------- fused window attention (fp32) ----------
// One block per (b, h). qkv layout (B_, N, 3, H, hd) flat.
__global__ __launch_bounds__(256) void attn_fused_kernel(
    const float* __restrict__ qkv, const float* __restrict__ mask,
    const float* __restrict__ bias_table, float* __restrict__ attn_out,
    float* __restrict__ o_buf) {
  const int b = blockIdx.x / HEADS;
  const int h = blockIdx.x % HEADS;
  const int tid = threadIdx.x;

  __shared__ float qs[NN][HD + 1];
  __shared__ float ks[NN][HD + 1];
  __shared__ float vs[NN][HD + 1];
  __shared__ float S[NN][NN + 4];  // stride 53 (odd vs 32 banks)
  __shared__ float rinv[NN];

  const float scale = 0.17677669529663687f;  // 32^-0.5

  for (int idx = tid; idx < NN * (HD / 4); idx += 256) {
    const int n = idx / (HD / 4);
    const int d4 = (idx % (HD / 4)) * 4;
    const size_t base = ((size_t)(b * NN + n) * 3) * CC + h * HD + d4;
    const float4 qv = *reinterpret_cast<const float4*>(&qkv[base]);
    const float4 kv = *reinterpret_cast<const float4*>(&qkv[base + CC]);
    const float4 vv = *reinterpret_cast<const float4*>(&qkv[base + 2 * CC]);
    qs[n][d4 + 0] = qv.x * scale; qs[n][d4 + 1] = qv.y * scale;
    qs[n][d4 + 2] = qv.z * scale; qs[n][d4 + 3] = qv.w * scale;
    ks[n][d4 + 0] = kv.x; ks[n][d4 + 1] = kv.y;
    ks[n][d4 + 2] = kv.z; ks[n][d4 + 3] = kv.w;
    vs[n][d4 + 0] = vv.x; vs[n][d4 + 1] = vv.y;
    vs[n][d4 + 2] = vv.z; vs[n][d4 + 3] = vv.w;
  }
  __syncthreads();

  // S = q@k^T + rel_bias + window mask
  const float* mrow = &mask[(size_t)(b % NW) * NN * NN];
  for (int idx = tid; idx < NN * NN; idx += 256) {
    const int i = idx / NN, j = idx % NN;
    float s = 0.f;
#pragma unroll
    for (int d = 0; d < HD; ++d) s = fmaf(qs[i][d], ks[j][d], s);
    const int ih = i / WW, iw = i % WW, jh = j / WW, jw = j % WW;
    const int rel = (ih - jh + WH - 1) * (2 * WW - 1) + (iw - jw + WW - 1);
    s += bias_table[rel * HEADS + h] + mrow[idx];
    S[i][j] = s;
  }
  __syncthreads();

  // Row softmax: 4 threads per row + shfl_xor reduce (groups stay in-wave).
  if (tid < 4 * NN) {
    const int i = tid >> 2, t = tid & 3;
    float m = -1e30f;
    for (int j = t; j < NN; j += 4) m = fmaxf(m, S[i][j]);
    m = fmaxf(m, __shfl_xor(m, 1));
    m = fmaxf(m, __shfl_xor(m, 2));
    float sum = 0.f;
    for (int j = t; j < NN; j += 4) {
      const float e = __expf(S[i][j] - m);
      S[i][j] = e;
      sum += e;
    }
    sum += __shfl_xor(sum, 1);
    sum += __shfl_xor(sum, 2);
    if (t == 0) rinv[i] = 1.0f / sum;
  }
  __syncthreads();

  // Normalize + write attn probs (nontemporal: never re-read).
  float* aout = &attn_out[(size_t)blockIdx.x * NN * NN];
  for (int idx = tid; idx < NN * NN; idx += 256) {
    const int i = idx / NN, j = idx % NN;
    const float p = S[i][j] * rinv[i];
    S[i][j] = p;
    __builtin_nontemporal_store(p, &aout[idx]);
  }
  __syncthreads();

  // O = P @ v -> o_buf[b*N + i][h*32 + d]  (fp32)
  for (int idx = tid; idx < NN * HD; idx += 256) {
    const int i = idx / HD, d = idx % HD;
    float acc = 0.f;
    for (int j = 0; j < NN; ++j) acc = fmaf(S[i][j], vs[j][d], acc);
    o_buf[((size_t)(b * NN) + i) * CC + h * HD + d] = acc;
  }
}

extern "C" void kernel_launch(void* const* d_in, const int* in_sizes, int n_in,
                              void* d_out, int out_size, void* d_ws,
                              size_t ws_size, hipStream_t stream) {
  const float* x = (const float*)d_in[0];
  // d_in[1] = input_shape (unused; conv path not exercised)
  const float* mask = (const float*)d_in[2];
  const float* Wqkv = (const float*)d_in[3];
  const float* bqkv = (const float*)d_in[4];
  const float* bias_table = (const float*)d_in[5];
  const float* Wproj = (const float*)d_in[6];
  const float* bproj = (const float*)d_in[7];

  const int B_ = in_sizes[0] / (NN * CC);  // 2048
  const int M = B_ * NN;                   // 100352

  float* out = (float*)d_out;              // (B_, N, C)
  float* attn = out + (size_t)M * CC;      // (B_, H, N, N)

  // workspace layout (fp32 words):
  //   qkv_buf : M*3C  = 462.4 MB
  //   o_buf   : M*C   = 154.1 MB
  //   weight splits (u16) = 3.4 MB     (total ~620 MB)
  float* qkv_buf = (float*)d_ws;
  float* o_buf = qkv_buf + (size_t)M * 3 * CC;
  unsigned short* wqkvt_h = (unsigned short*)(o_buf + (size_t)M * CC);
  unsigned short* wqkvt_l = wqkvt_h + (size_t)3 * CC * CC;
  unsigned short* wprojt_h = wqkvt_l + (size_t)3 * CC * CC;
  unsigned short* wprojt_l = wprojt_h + (size_t)CC * CC;

  // 0) split + transpose weights (tiny)
  split_wt_kernel<<<(3 * CC * CC + 255) / 256, 256, 0, stream>>>(
      Wqkv, wqkvt_h, wqkvt_l, CC, 3 * CC);
  split_wt_kernel<<<(CC * CC + 255) / 256, 256, 0, stream>>>(
      Wproj, wprojt_h, wprojt_l, CC, CC);

  // 1) qkv = x @ Wqkv + bqkv   (MFMA bf16x3; qkv_buf re-read -> cached stores)
  {
    const int tilesM = M / 128, tilesN = (3 * CC) / 128;  // 784 x 9
    const int nwg = tilesM * tilesN;                      // 7056, %8==0
    gemm_bf16x3_kernel<false><<<nwg, 256, 0, stream>>>(
        x, wqkvt_h, wqkvt_l, bqkv, qkv_buf, M, 3 * CC, CC, tilesN, nwg / 8);
  }
  // 2) fused attention (writes attn probs + per-head outputs)
  {
    dim3 grid(B_ * HEADS);
    attn_fused_kernel<<<grid, 256, 0, stream>>>(qkv_buf, mask, bias_table,
                                                attn, o_buf);
  }
  // 3) out = o @ Wproj + bproj  (MFMA bf16x3; out never re-read -> NT stores)
  {
    const int tilesM = M / 128, tilesN = CC / 128;  // 784 x 3
    const int nwg = tilesM * tilesN;                // 2352, %8==0
    gemm_bf16x3_kernel<true><<<nwg, 256, 0, stream>>>(
        o_buf, wprojt_h, wprojt_l, bproj, out, M, CC, CC, tilesN, nwg / 8);
  }
}

// Round 15
// 1181.378 us; speedup vs baseline: 1.1515x; 1.1515x over previous
//
#include <hip/hip_runtime.h>
#include <math.h>

#define WH 7
#define WW 7
#define NN 49
#define HEADS 12
#define HD 32
#define CC 384
#define NW 256

typedef short s16x8 __attribute__((ext_vector_type(8)));
typedef unsigned short u16x8 __attribute__((ext_vector_type(8)));
typedef float f32x4 __attribute__((ext_vector_type(4)));

// fp32 -> bf16 (round-to-nearest-even), bit-level
__device__ __forceinline__ unsigned short f2bf(float x) {
  unsigned u = __builtin_bit_cast(unsigned, x);
  u += 0x7fffu + ((u >> 16) & 1u);
  return (unsigned short)(u >> 16);
}
__device__ __forceinline__ float bf2f(unsigned short b) {
  unsigned u = ((unsigned)b) << 16;
  return __builtin_bit_cast(float, u);
}

// ---------- transpose + hi/lo split of a weight matrix ----------
__global__ void split_wt_kernel(const float* __restrict__ W,
                                unsigned short* __restrict__ Th,
                                unsigned short* __restrict__ Tl,
                                int K, int N) {
  const int idx = blockIdx.x * 256 + threadIdx.x;
  if (idx >= K * N) return;
  const int k = idx / N, n = idx % N;
  const float v = W[idx];
  const unsigned short h = f2bf(v);
  const size_t t = (size_t)n * K + k;
  Th[t] = h;
  Tl[t] = f2bf(v - bf2f(h));
}

// ---------- GEMM via bf16x3 MFMA, register-prefetched staging ----------
// C[M][N] = A[M][K](fp32, split in-kernel) @ Bt[N][K](pre-split bf16) + bias
// 128x128 tile, 256 thr (4 waves 2x2 of 64x64), K-step 32, XCD swizzle.
template <bool NT>
__global__ __launch_bounds__(256) void gemm_bf16x3_kernel(
    const float* __restrict__ A, const unsigned short* __restrict__ Bth,
    const unsigned short* __restrict__ Btl, const float* __restrict__ bias,
    float* __restrict__ C, int M, int N, int K, int tilesN, int chunk) {
  __shared__ unsigned short Ash[128][40];
  __shared__ unsigned short Asl[128][40];
  __shared__ unsigned short Bsh[128][40];
  __shared__ unsigned short Bsl[128][40];

  const int lin = blockIdx.x;
  const int logical = (lin & 7) * chunk + (lin >> 3);
  const int bm = (logical / tilesN) * 128;
  const int bn = (logical % tilesN) * 128;

  const int tid = threadIdx.x;
  const int lane = tid & 63;
  const int wv = tid >> 6;
  const int wm = (wv >> 1) * 64;
  const int wn = (wv & 1) * 64;
  const int fr = lane & 15;
  const int g8 = (lane >> 4) * 8;

  const int srow = tid >> 1;
  const int sc16 = (tid & 1) * 16;

  const float* aptr = &A[(size_t)(bm + srow) * K + sc16];
  const unsigned short* bhp = &Bth[(size_t)(bn + srow) * K + sc16];
  const unsigned short* blp = &Btl[(size_t)(bn + srow) * K + sc16];

  // register-staged tile (prefetch buffer)
  f32x4 ar[4];
  u16x8 brh[2], brl[2];
  ar[0] = *(const f32x4*)&aptr[0];
  ar[1] = *(const f32x4*)&aptr[4];
  ar[2] = *(const f32x4*)&aptr[8];
  ar[3] = *(const f32x4*)&aptr[12];
  brh[0] = *(const u16x8*)&bhp[0];
  brh[1] = *(const u16x8*)&bhp[8];
  brl[0] = *(const u16x8*)&blp[0];
  brl[1] = *(const u16x8*)&blp[8];

  f32x4 acc[4][4] = {};

  for (int k0 = 0; k0 < K; k0 += 32) {
    // write staged regs -> LDS (A: hi/lo split on VALU)
    {
      float v[16];
      *(f32x4*)&v[0] = ar[0];
      *(f32x4*)&v[4] = ar[1];
      *(f32x4*)&v[8] = ar[2];
      *(f32x4*)&v[12] = ar[3];
      unsigned short hh[16], ll[16];
#pragma unroll
      for (int i = 0; i < 16; ++i) {
        hh[i] = f2bf(v[i]);
        ll[i] = f2bf(v[i] - bf2f(hh[i]));
      }
      *(u16x8*)&Ash[srow][sc16] = *(u16x8*)&hh[0];
      *(u16x8*)&Ash[srow][sc16 + 8] = *(u16x8*)&hh[8];
      *(u16x8*)&Asl[srow][sc16] = *(u16x8*)&ll[0];
      *(u16x8*)&Asl[srow][sc16 + 8] = *(u16x8*)&ll[8];
      *(u16x8*)&Bsh[srow][sc16] = brh[0];
      *(u16x8*)&Bsh[srow][sc16 + 8] = brh[1];
      *(u16x8*)&Bsl[srow][sc16] = brl[0];
      *(u16x8*)&Bsl[srow][sc16 + 8] = brl[1];
    }
    __syncthreads();

    // prefetch next K-step; latency hides under frag reads + MFMA
    if (k0 + 32 < K) {
      const int kn = k0 + 32;
      ar[0] = *(const f32x4*)&aptr[kn];
      ar[1] = *(const f32x4*)&aptr[kn + 4];
      ar[2] = *(const f32x4*)&aptr[kn + 8];
      ar[3] = *(const f32x4*)&aptr[kn + 12];
      brh[0] = *(const u16x8*)&bhp[kn];
      brh[1] = *(const u16x8*)&bhp[kn + 8];
      brl[0] = *(const u16x8*)&blp[kn];
      brl[1] = *(const u16x8*)&blp[kn + 8];
    }

    s16x8 ah[4], al[4];
#pragma unroll
    for (int m = 0; m < 4; ++m) {
      ah[m] = *(const s16x8*)&Ash[wm + m * 16 + fr][g8];
      al[m] = *(const s16x8*)&Asl[wm + m * 16 + fr][g8];
    }
#pragma unroll
    for (int n = 0; n < 4; ++n) {
      const s16x8 bh = *(const s16x8*)&Bsh[wn + n * 16 + fr][g8];
      const s16x8 bl = *(const s16x8*)&Bsl[wn + n * 16 + fr][g8];
#pragma unroll
      for (int m = 0; m < 4; ++m) {
        acc[m][n] = __builtin_amdgcn_mfma_f32_16x16x32_bf16(ah[m], bh,
                                                            acc[m][n], 0, 0, 0);
        acc[m][n] = __builtin_amdgcn_mfma_f32_16x16x32_bf16(ah[m], bl,
                                                            acc[m][n], 0, 0, 0);
        acc[m][n] = __builtin_amdgcn_mfma_f32_16x16x32_bf16(al[m], bh,
                                                            acc[m][n], 0, 0, 0);
      }
    }
    __syncthreads();
  }

  // epilogue: D row = (lane>>4)*4 + reg, col = lane&15 [HW-verified]
  const int r0 = (lane >> 4) * 4;
#pragma unroll
  for (int m = 0; m < 4; ++m) {
#pragma unroll
    for (int r = 0; r < 4; ++r) {
      const int row = bm + wm + m * 16 + r0 + r;
      float* dst = &C[(size_t)row * N + bn + wn];
#pragma unroll
      for (int n = 0; n < 4; ++n) {
        const float val = acc[m][n][r] + bias[bn + wn + n * 16 + fr];
        if (NT)
          __builtin_nontemporal_store(val, &dst[n * 16 + fr]);
        else
          dst[n * 16 + fr] = val;
      }
    }
  }
}

// ---------- fused window attention via MFMA ----------
// One block (256 thr, 4 waves) per (b,h). Wave w owns S/O rows 16w..16w+15.
// S tile 64x64 (rows/cols >=49 padded with -1e30 -> P exactly 0).
// QK^T and PV both bf16x3 (Markidis) -> fp32-grade accuracy.
__global__ __launch_bounds__(256) void attn_mfma_kernel(
    const float* __restrict__ qkv, const float* __restrict__ mask,
    const float* __restrict__ bias_table, float* __restrict__ attn_out,
    float* __restrict__ o_buf) {
  const int b = blockIdx.x / HEADS;
  const int h = blockIdx.x % HEADS;
  const int tid = threadIdx.x;
  const int lane = tid & 63;
  const int wv = tid >> 6;
  const int fr = lane & 15;
  const int grp = lane >> 4;

  __shared__ unsigned short qh[64][40], ql[64][40];  // q rows (A-frag layout)
  __shared__ unsigned short kh[64][40], kl[64][40];  // k rows (B-frag layout)
  __shared__ unsigned short vh[32][72], vl[32][72];  // v^T: [d][key]
  __shared__ unsigned short Ph[64][72], Pl[64][72];  // probs bf16 hi/lo

  const float scale = 0.17677669529663687f;  // 32^-0.5

  // ---- stage q (pre-scaled), k, v^T; all hi/lo bf16 ----
  for (int idx = tid; idx < NN * (HD / 4); idx += 256) {  // 392 items
    const int n = idx >> 3, d4 = (idx & 7) * 4;
    const size_t base = ((size_t)(b * NN + n) * 3) * CC + h * HD + d4;
    const float4 qv = *reinterpret_cast<const float4*>(&qkv[base]);
    const float4 kv = *reinterpret_cast<const float4*>(&qkv[base + CC]);
    const float4 vv = *reinterpret_cast<const float4*>(&qkv[base + 2 * CC]);
    const float qa[4] = {qv.x * scale, qv.y * scale, qv.z * scale,
                         qv.w * scale};
    const float ka[4] = {kv.x, kv.y, kv.z, kv.w};
    const float va[4] = {vv.x, vv.y, vv.z, vv.w};
#pragma unroll
    for (int c = 0; c < 4; ++c) {
      unsigned short t;
      t = f2bf(qa[c]); qh[n][d4 + c] = t; ql[n][d4 + c] = f2bf(qa[c] - bf2f(t));
      t = f2bf(ka[c]); kh[n][d4 + c] = t; kl[n][d4 + c] = f2bf(ka[c] - bf2f(t));
      t = f2bf(va[c]); vh[d4 + c][n] = t; vl[d4 + c][n] = f2bf(va[c] - bf2f(t));
    }
  }
  // zero v^T padding keys 49..63 (P=0 there, but garbage could be NaN)
  for (int idx = tid; idx < 32 * 15; idx += 256) {
    const int d = idx / 15, kk = NN + idx % 15;
    vh[d][kk] = 0;
    vl[d][kk] = 0;
  }
  __syncthreads();

  // ---- QK^T (bf16x3): wave wv computes S rows 16wv..16wv+15, cols 0..63 ----
  f32x4 sacc[4] = {};
  {
    const s16x8 aqh = *(const s16x8*)&qh[wv * 16 + fr][grp * 8];
    const s16x8 aql = *(const s16x8*)&ql[wv * 16 + fr][grp * 8];
#pragma unroll
    for (int n = 0; n < 4; ++n) {
      const s16x8 bh = *(const s16x8*)&kh[n * 16 + fr][grp * 8];
      const s16x8 bl = *(const s16x8*)&kl[n * 16 + fr][grp * 8];
      sacc[n] = __builtin_amdgcn_mfma_f32_16x16x32_bf16(aqh, bh, sacc[n], 0, 0, 0);
      sacc[n] = __builtin_amdgcn_mfma_f32_16x16x32_bf16(aqh, bl, sacc[n], 0, 0, 0);
      sacc[n] = __builtin_amdgcn_mfma_f32_16x16x32_bf16(aql, bh, sacc[n], 0, 0, 0);
    }
  }

  // ---- rel-bias + window mask + padding (C/D: row=grp*4+reg, col=n*16+fr) --
  const float* mrow = &mask[(size_t)(b % NW) * NN * NN];
  const int rowbase = wv * 16 + grp * 4;
  float sv[4][4];
#pragma unroll
  for (int n = 0; n < 4; ++n) {
    const int col = n * 16 + fr;
#pragma unroll
    for (int r = 0; r < 4; ++r) {
      const int row = rowbase + r;
      float s = -1e30f;
      if (row < NN && col < NN) {
        const int rel = (row / WW - col / WW + WH - 1) * (2 * WW - 1) +
                        (row % WW - col % WW + WW - 1);
        s = sacc[n][r] + bias_table[rel * HEADS + h] + mrow[row * NN + col];
      }
      sv[n][r] = s;
    }
  }

  // ---- softmax per row; rows live in 16-lane groups -> shfl_xor 1,2,4,8 ----
  float* aout = &attn_out[(size_t)blockIdx.x * NN * NN];
#pragma unroll
  for (int r = 0; r < 4; ++r) {
    float m = fmaxf(fmaxf(sv[0][r], sv[1][r]), fmaxf(sv[2][r], sv[3][r]));
    m = fmaxf(m, __shfl_xor(m, 1));
    m = fmaxf(m, __shfl_xor(m, 2));
    m = fmaxf(m, __shfl_xor(m, 4));
    m = fmaxf(m, __shfl_xor(m, 8));
    float p[4], sum = 0.f;
#pragma unroll
    for (int n = 0; n < 4; ++n) {
      p[n] = __expf(sv[n][r] - m);
      sum += p[n];
    }
    sum += __shfl_xor(sum, 1);
    sum += __shfl_xor(sum, 2);
    sum += __shfl_xor(sum, 4);
    sum += __shfl_xor(sum, 8);
    const float rinv = 1.0f / sum;
    const int row = rowbase + r;
#pragma unroll
    for (int n = 0; n < 4; ++n) {
      const float pv = p[n] * rinv;  // pad cols: exp(-1e30-m)=0 exactly
      const int col = n * 16 + fr;
      if (row < NN && col < NN)
        __builtin_nontemporal_store(pv, &aout[row * NN + col]);
      const unsigned short t = f2bf(pv);
      Ph[row][col] = t;
      Pl[row][col] = f2bf(pv - bf2f(t));
    }
  }
  __syncthreads();  // drain P writes (rows are wave-private; belt+braces)

  // ---- PV (bf16x3): O rows 16wv.., cols d=0..31 ----
  f32x4 oacc[2] = {};
#pragma unroll
  for (int kk = 0; kk < 2; ++kk) {
    const s16x8 pah = *(const s16x8*)&Ph[wv * 16 + fr][kk * 32 + grp * 8];
    const s16x8 pal = *(const s16x8*)&Pl[wv * 16 + fr][kk * 32 + grp * 8];
#pragma unroll
    for (int n = 0; n < 2; ++n) {
      const s16x8 vbh = *(const s16x8*)&vh[n * 16 + fr][kk * 32 + grp * 8];
      const s16x8 vbl = *(const s16x8*)&vl[n * 16 + fr][kk * 32 + grp * 8];
      oacc[n] = __builtin_amdgcn_mfma_f32_16x16x32_bf16(pah, vbh, oacc[n], 0, 0, 0);
      oacc[n] = __builtin_amdgcn_mfma_f32_16x16x32_bf16(pah, vbl, oacc[n], 0, 0, 0);
      oacc[n] = __builtin_amdgcn_mfma_f32_16x16x32_bf16(pal, vbh, oacc[n], 0, 0, 0);
    }
  }

  // ---- O epilogue -> o_buf[b*N + row][h*32 + d] ----
#pragma unroll
  for (int n = 0; n < 2; ++n) {
#pragma unroll
    for (int r = 0; r < 4; ++r) {
      const int row = rowbase + r;
      if (row < NN) {
        o_buf[((size_t)(b * NN) + row) * CC + h * HD + n * 16 + fr] =
            oacc[n][r];
      }
    }
  }
}

extern "C" void kernel_launch(void* const* d_in, const int* in_sizes, int n_in,
                              void* d_out, int out_size, void* d_ws,
                              size_t ws_size, hipStream_t stream) {
  const float* x = (const float*)d_in[0];
  const float* mask = (const float*)d_in[2];
  const float* Wqkv = (const float*)d_in[3];
  const float* bqkv = (const float*)d_in[4];
  const float* bias_table = (const float*)d_in[5];
  const float* Wproj = (const float*)d_in[6];
  const float* bproj = (const float*)d_in[7];

  const int B_ = in_sizes[0] / (NN * CC);  // 2048
  const int M = B_ * NN;                   // 100352

  float* out = (float*)d_out;              // (B_, N, C)
  float* attn = out + (size_t)M * CC;      // (B_, H, N, N)

  float* qkv_buf = (float*)d_ws;
  float* o_buf = qkv_buf + (size_t)M * 3 * CC;
  unsigned short* wqkvt_h = (unsigned short*)(o_buf + (size_t)M * CC);
  unsigned short* wqkvt_l = wqkvt_h + (size_t)3 * CC * CC;
  unsigned short* wprojt_h = wqkvt_l + (size_t)3 * CC * CC;
  unsigned short* wprojt_l = wprojt_h + (size_t)CC * CC;

  // 0) split + transpose weights (tiny)
  split_wt_kernel<<<(3 * CC * CC + 255) / 256, 256, 0, stream>>>(
      Wqkv, wqkvt_h, wqkvt_l, CC, 3 * CC);
  split_wt_kernel<<<(CC * CC + 255) / 256, 256, 0, stream>>>(
      Wproj, wprojt_h, wprojt_l, CC, CC);

  // 1) qkv = x @ Wqkv + bqkv
  {
    const int tilesM = M / 128, tilesN = (3 * CC) / 128;  // 784 x 9
    const int nwg = tilesM * tilesN;                      // 7056, %8==0
    gemm_bf16x3_kernel<false><<<nwg, 256, 0, stream>>>(
        x, wqkvt_h, wqkvt_l, bqkv, qkv_buf, M, 3 * CC, CC, tilesN, nwg / 8);
  }
  // 2) fused attention (MFMA)
  {
    dim3 grid(B_ * HEADS);
    attn_mfma_kernel<<<grid, 256, 0, stream>>>(qkv_buf, mask, bias_table, attn,
                                               o_buf);
  }
  // 3) out = o @ Wproj + bproj (NT: out never re-read)
  {
    const int tilesM = M / 128, tilesN = CC / 128;  // 784 x 3
    const int nwg = tilesM * tilesN;                // 2352, %8==0
    gemm_bf16x3_kernel<true><<<nwg, 256, 0, stream>>>(
        o_buf, wprojt_h, wprojt_l, bproj, out, M, CC, CC, tilesN, nwg / 8);
  }
}